// Round 7
// baseline (207.315 us; speedup 1.0000x reference)
//
#include <hip/hip_runtime.h>
#include <hip/hip_bf16.h>

typedef float f32x4 __attribute__((ext_vector_type(4)));
typedef __bf16 bf16x8 __attribute__((ext_vector_type(8)));

#define AS3(p) ((__attribute__((address_space(3))) void*)(p))
#define AS1(p) ((const __attribute__((address_space(1))) void*)(p))

__device__ __forceinline__ unsigned short f2bf(float f) {
    unsigned u = __float_as_uint(f);
    return (unsigned short)((u + 0x7fffu + ((u >> 16) & 1u)) >> 16);  // RNE
}

__device__ __forceinline__ unsigned long long sort_key(float v, int idx) {
    unsigned ub = __float_as_uint(v);
    unsigned m  = (ub & 0x80000000u) ? ~ub : (ub | 0x80000000u);  // asc map
    return ((unsigned long long)(~m) << 12) | (unsigned)idx;      // desc, stable
}

// ---------------------------------------------------------------------------
// Fused prep: one dispatch.
//   blocks [0,1024):      x fp32 -> bf16
//   blocks [1024,2304):   W1/W2 transpose+convert (64x64 tiles)
//   block  2304:          zero scores accumulator + posg
// ---------------------------------------------------------------------------
__global__ __launch_bounds__(256) void prep_all(
    const float* __restrict__ x, unsigned short* __restrict__ xb,
    const float* __restrict__ W1, unsigned short* __restrict__ W1t,
    const float* __restrict__ W2, unsigned short* __restrict__ W2t,
    float* __restrict__ sc, int* __restrict__ posg)
{
    __shared__ float tile[64][65];
    const int bx = blockIdx.x;
    const int t = threadIdx.x;

    if (bx < 1024) {                       // convert x
        int i = bx * 2048 + t * 8;
        float4 v0 = *(const float4*)(x + i);
        float4 v1 = *(const float4*)(x + i + 4);
        ushort4 o0 = { f2bf(v0.x), f2bf(v0.y), f2bf(v0.z), f2bf(v0.w) };
        ushort4 o1 = { f2bf(v1.x), f2bf(v1.y), f2bf(v1.z), f2bf(v1.w) };
        *(ushort4*)(xb + i)     = o0;
        *(ushort4*)(xb + i + 4) = o1;
        return;
    }
    if (bx == 2304) {                      // zero sc + posg
        float4 z = {0.f, 0.f, 0.f, 0.f};
        int4 zi = {0, 0, 0, 0};
        #pragma unroll
        for (int i = 0; i < 4; ++i) {
            *(float4*)(sc + t * 16 + i * 4)  = z;
            *(int4*)(posg + t * 16 + i * 4)  = zi;
        }
        return;
    }
    // transpose tiles
    int idx = bx - 1024;
    int ty = idx >> 5;                     // 0..39
    int txi = idx & 31;                    // 0..31
    const float* W; unsigned short* Wt; int K, N, by;
    if (ty < 8) { W = W1; Wt = W1t; K = 512;  N = 2048; by = ty; }
    else        { W = W2; Wt = W2t; K = 2048; N = 2048; by = ty - 8; }

    const int col4 = t & 15;
    const int row  = t >> 4;
    #pragma unroll
    for (int i = 0; i < 4; ++i) {
        int r = row + i * 16;
        float4 v = *(const float4*)(W + (size_t)(by * 64 + r) * N + txi * 64 + col4 * 4);
        tile[r][col4 * 4 + 0] = v.x;
        tile[r][col4 * 4 + 1] = v.y;
        tile[r][col4 * 4 + 2] = v.z;
        tile[r][col4 * 4 + 3] = v.w;
    }
    __syncthreads();
    #pragma unroll
    for (int i = 0; i < 4; ++i) {
        int r = row + i * 16;
        ushort4 o = { f2bf(tile[col4 * 4 + 0][r]), f2bf(tile[col4 * 4 + 1][r]),
                      f2bf(tile[col4 * 4 + 2][r]), f2bf(tile[col4 * 4 + 3][r]) };
        *(ushort4*)(Wt + (size_t)(txi * 64 + r) * K + by * 64 + col4 * 4) = o;
    }
}

// ---------------------------------------------------------------------------
// bf16 MFMA GEMM, 256x128 tile, BK=64. R7: A-OPERAND IN REGISTERS.
// R4 post-mortem arithmetic: per K-tile per CU, LDS traffic (A+B reads
// 128 KB + staging writes 48 KB ~ 1400 cyc @128B/cyc) >> MFMA (310
// cyc/SIMD) -> LDS-BW-bound, which capped R4 at ~46% and made R5/R6
// schedule/shape edits moot. Fix: A is shared by only 2 waves, so each
// wave loads its own A frags global->reg (8 x dwordx4/tile, prefetch
// distance 1); LDS keeps only B (3 x 16 KB buffers, prefetch distance 2,
// counted vmcnt(2) steady state — a-loads pinned BEFORE B-stage via
// sched_barrier so the count is exact; reg-load correctness is
// independently guaranteed by compiler auto-waitcnt). LDS/tile drops
// 176->80 KB. B path/swizzle/barrier/epilogue identical to R4 ->
// bit-identical results.
// 512 thr = 8 waves (4M x 2N, per-wave 64x64), grid 256 = 1 block/CU.
// T1 XCD swizzle (nwg=256, bijective). MODE 0: relu GEMM; MODE 1: fused
// layer-3 rank-1 epilogue.
// ---------------------------------------------------------------------------
#define GB_WAITV(n) { asm volatile("s_waitcnt vmcnt(" #n ")" ::: "memory"); \
                      __builtin_amdgcn_sched_barrier(0); }

template <int MODE>
__global__ __launch_bounds__(512, 2) void gemm_bf16_mfma(
    const unsigned short* __restrict__ A, const unsigned short* __restrict__ Bt,
    const float* __restrict__ bias, unsigned short* __restrict__ Cbf,
    const float* __restrict__ w3, float* __restrict__ scores,
    int M, int N, int K)
{
    __shared__ __align__(16) unsigned short lds3[3][128 * 64];   // 3 x 16 KB (B only)

    const int tid = threadIdx.x;
    const int wave = tid >> 6, lane = tid & 63;

    // T1: XCD-aware block swizzle (bijective: nwg % 8 == 0)
    const unsigned nwg = gridDim.x * gridDim.y;
    const unsigned bid = blockIdx.y * gridDim.x + blockIdx.x;
    const unsigned sbid = (bid & 7u) * (nwg >> 3) + (bid >> 3);
    const int bn = sbid % gridDim.x;
    const int bm = sbid / gridDim.x;

    const int wm = (wave >> 1) * 64;     // 0,64,128,192
    const int wn = (wave & 1) * 64;      // 0,64

    const unsigned short* Ablk = A  + (size_t)(bm * 256) * K;
    const unsigned short* Bblk = Bt + (size_t)(bn * 128) * K;

    const int lc  = lane & 15;
    const int rl4 = lane >> 4;                     // 0..3
    const int srow = lane >> 3;                    // 0..7
    const int sgc  = ((lane & 7) ^ srow) << 3;     // pre-swizzled src chunk (elems)

    // per-lane A base: row = wm + lc (+ mt*16), k = rl4*8 (+ kk*32 + t*64)
    const unsigned short* Aln = Ablk + (size_t)(wm + lc) * K + rl4 * 8;

    f32x4 acc[4][4] = {};
    const int nt = K >> 6;

    unsigned short *Bc = lds3[0], *Bn = lds3[1], *Bsp = lds3[2];

    // stage B-tile (128 rows x 64): wave covers rows [wave*16, +16), 2 loads
    #define STG_B(k0, D) {                                                     \
        _Pragma("unroll")                                                      \
        for (int i = 0; i < 2; ++i) {                                          \
            const int rb = wave * 16 + i * 8 + srow;                           \
            __builtin_amdgcn_global_load_lds(                                  \
                AS1(Bblk + (size_t)rb * K + (k0) + sgc),                       \
                AS3((D) + (wave * 16 + i * 8) * 64), 16, 0, 0);                \
        } }

    // prologue: B(0), a(0), B(1)  -> queue [B0 2, a0 8, B1 2]
    STG_B(0, Bc);
    bf16x8 a_cur[4][2];
    #pragma unroll
    for (int mt = 0; mt < 4; ++mt)
        #pragma unroll
        for (int kk = 0; kk < 2; ++kk)
            a_cur[mt][kk] = *(const bf16x8*)(Aln + (size_t)(mt * 16) * K + kk * 32);
    __builtin_amdgcn_sched_barrier(0);
    if (nt > 1) STG_B(64, Bn);

    for (int t = 0; t < nt; ++t) {
        // steady state: drain a(t)+B(t), keep B(t+1)'s 2 stages in flight
        if (t < nt - 1) { GB_WAITV(2); } else { GB_WAITV(0); }
        __builtin_amdgcn_s_barrier();

        // issue next-tile A reg loads (8 x dwordx4)
        bf16x8 a_nxt[4][2];
        if (t + 1 < nt) {
            const unsigned short* ap = Aln + (size_t)(t + 1) * 64;
            #pragma unroll
            for (int mt = 0; mt < 4; ++mt)
                #pragma unroll
                for (int kk = 0; kk < 2; ++kk)
                    a_nxt[mt][kk] = *(const bf16x8*)(ap + (size_t)(mt * 16) * K + kk * 32);
        }
        __builtin_amdgcn_sched_barrier(0);   // pin: a-loads BEFORE B-stage
        if (t + 2 < nt) { STG_B((t + 2) << 6, Bsp); }
        __builtin_amdgcn_sched_barrier(0);

        // compute on B(t) + a_cur: 2 k-steps x {4 ds_read_b128, 16 MFMA}
        #pragma unroll
        for (int s = 0; s < 2; ++s) {
            const int rsw = (((s * 4 + rl4) ^ (lc & 7)) << 3);
            bf16x8 b[4];
            #pragma unroll
            for (int n2 = 0; n2 < 4; ++n2)
                b[n2] = *(const bf16x8*)(Bc + (wn + n2 * 16 + lc) * 64 + rsw);
            __builtin_amdgcn_s_setprio(1);
            #pragma unroll
            for (int mt = 0; mt < 4; ++mt)
                #pragma unroll
                for (int n2 = 0; n2 < 4; ++n2)
                    acc[mt][n2] = __builtin_amdgcn_mfma_f32_16x16x32_bf16(
                        a_cur[mt][s], b[n2], acc[mt][n2], 0, 0, 0);
            __builtin_amdgcn_s_setprio(0);
        }

        // advance A regs; rotate B buffers (consumed -> spare)
        if (t + 1 < nt) {
            #pragma unroll
            for (int mt = 0; mt < 4; ++mt)
                #pragma unroll
                for (int kk = 0; kk < 2; ++kk)
                    a_cur[mt][kk] = a_nxt[mt][kk];
        }
        unsigned short* tmp = Bc; Bc = Bn; Bn = Bsp; Bsp = tmp;
    }

    #undef STG_B

    // Epilogue. C/D frag: col = lane&15, row = (lane>>4)*4 + reg  [m89]
    const int cm0 = bm * 256 + wm;
    const int cn0 = bn * 128 + wn;
    const int lr = (lane >> 4) * 4;

    if (MODE == 0) {
        #pragma unroll
        for (int j = 0; j < 4; ++j) {
            float bv = bias[cn0 + j * 16 + lc];
            #pragma unroll
            for (int mt = 0; mt < 4; ++mt)
                #pragma unroll
                for (int r = 0; r < 4; ++r) {
                    float v = fmaxf(acc[mt][j][r] + bv, 0.0f);
                    size_t idx = (size_t)(cm0 + mt * 16 + lr + r) * N + cn0 + j * 16 + lc;
                    Cbf[idx] = f2bf(v);
                }
        }
    } else {
        float bv[4], w3v[4];
        #pragma unroll
        for (int j = 0; j < 4; ++j) {
            bv[j]  = bias[cn0 + j * 16 + lc];
            w3v[j] = w3[cn0 + j * 16 + lc];
        }
        #pragma unroll
        for (int mt = 0; mt < 4; ++mt)
            #pragma unroll
            for (int r = 0; r < 4; ++r) {
                float p = 0.0f;
                #pragma unroll
                for (int j = 0; j < 4; ++j)
                    p += fmaxf(acc[mt][j][r] + bv[j], 0.0f) * w3v[j];
                p += __shfl_xor(p, 1);
                p += __shfl_xor(p, 2);
                p += __shfl_xor(p, 4);
                p += __shfl_xor(p, 8);
                if (lc == 0)
                    atomicAdd(&scores[cm0 + mt * 16 + lr + r], p);
            }
    }
}

// ---------------------------------------------------------------------------
// Fused finalize + rank count, 2-D tiled (unchanged).
// ---------------------------------------------------------------------------
__global__ __launch_bounds__(256) void rank_count(
    const float* __restrict__ sc, const float* __restrict__ b3,
    float* __restrict__ out_scores, int* __restrict__ posg)
{
    __shared__ unsigned long long kj[256];
    const int t = threadIdx.x;
    const int bi = blockIdx.x, bj = blockIdx.y;
    const int i = bi * 256 + t;
    const float b3v = b3[0];

    {
        int j = bj * 256 + t;
        kj[t] = sort_key(sc[j] + b3v, j);
    }
    float vi = sc[i] + b3v;
    if (bj == 0) out_scores[i] = vi;
    const unsigned long long mykey = sort_key(vi, i);
    __syncthreads();

    int cnt = 0;
    #pragma unroll 32
    for (int j = 0; j < 256; ++j)
        cnt += (kj[j] < mykey) ? 1 : 0;
    atomicAdd(&posg[i], cnt);
}

// ---------------------------------------------------------------------------
// PAV + fill (latency redesign, verified R1: reg-chunk PAV + tree merge).
// ---------------------------------------------------------------------------
__global__ __launch_bounds__(1024) void pav_fill(
    const float* __restrict__ scores, const float* __restrict__ b3,
    const int* __restrict__ posg, float* __restrict__ rank_out)
{
    constexpr int n = 4096;
    __shared__ __align__(16) unsigned char lds[32768 + 16384 + 8192 + 512];
    double* bsum           = (double*)lds;                     // [4096]
    float*  svals          = (float*)(lds + 32768);            // [4096]
    unsigned short* bstart = (unsigned short*)(lds + 49152);   // [4096]
    unsigned short* cnt    = (unsigned short*)(lds + 57344);   // [256]

    const int tid = threadIdx.x;
    const float b3v = b3[0];

    // ---- scatter scores into sorted order (vectorized, 4/thread) ----
    {
        const int t = tid << 2;
        int4 p4 = *(const int4*)(posg + t);
        float4 s4 = *(const float4*)(scores + t);
        svals[p4.x] = s4.x + b3v;
        svals[p4.y] = s4.y + b3v;
        svals[p4.z] = s4.z + b3v;
        svals[p4.w] = s4.w + b3v;
    }
    __syncthreads();

    // ---- Phase A: per-lane PAV on 16-element chunks, 256 lanes ----
    if (tid < 256) {
        const int base = tid << 4;
        float vv[16];
        *(float4*)(vv + 0)  = *(const float4*)(svals + base + 0);
        *(float4*)(vv + 4)  = *(const float4*)(svals + base + 4);
        *(float4*)(vv + 8)  = *(const float4*)(svals + base + 8);
        *(float4*)(vv + 12) = *(const float4*)(svals + base + 12);
        int sp = 0;
        double tsum = 0.0; int tstart = 0;
        #pragma unroll
        for (int s = 0; s < 16; ++s) {
            const int i = base + s;
            double csum = (double)vv[s] - (double)(n - i);
            int cs = i;
            const int ce = i + 1;
            while (sp > 0 &&
                   tsum * (double)(ce - cs) <= csum * (double)(cs - tstart)) {
                csum += tsum; cs = tstart; --sp;
                if (sp > 0) { tsum = bsum[base + sp - 1]; tstart = bstart[base + sp - 1]; }
            }
            bsum[base + sp] = csum;                 // write-through push
            bstart[base + sp] = (unsigned short)cs;
            tsum = csum; tstart = cs; ++sp;
        }
        cnt[tid] = (unsigned short)sp;
    }
    __syncthreads();

    // ---- Phase B: tree merge, 8 rounds ----
    #pragma unroll 1
    for (int r = 0; r < 8; ++r) {
        const int m = 128 >> r;
        if (tid < m) {
            const int W  = 16 << r;
            const int L  = tid * (W << 1);    // left element/slot base
            const int Rb = L + W;             // right base
            int sp = cnt[L >> 4];
            const int cr = cnt[Rb >> 4];
            double tsum = bsum[L + sp - 1];
            int tstart = bstart[L + sp - 1];
            for (int j = 0; j < cr; ++j) {
                double csum = bsum[Rb + j];
                int cs = (int)bstart[Rb + j];
                const int ce = (j + 1 < cr) ? (int)bstart[Rb + j + 1] : (Rb + W);
                while (sp > 0 &&
                       tsum * (double)(ce - cs) <= csum * (double)(cs - tstart)) {
                    csum += tsum; cs = tstart; --sp;
                    if (sp > 0) { tsum = bsum[L + sp - 1]; tstart = bstart[L + sp - 1]; }
                }
                bsum[L + sp] = csum;
                bstart[L + sp] = (unsigned short)cs;
                tsum = csum; tstart = cs; ++sp;
            }
            cnt[L >> 4] = (unsigned short)sp;
        }
        __syncthreads();
    }

    // ---- gather: rank[t] = svals[p] - mean(block(p)), coalesced f4 writes ----
    const int nb = (int)cnt[0];
    {
        const int t = tid << 2;
        int4 p4 = *(const int4*)(posg + t);
        float4 o;
        int pa[4] = { p4.x, p4.y, p4.z, p4.w };
        float oa[4];
        #pragma unroll
        for (int e = 0; e < 4; ++e) {
            const int p = pa[e];
            int lo = 0, hi = nb - 1;
            while (lo < hi) {
                int mid = (lo + hi + 1) >> 1;
                if ((int)bstart[mid] <= p) lo = mid; else hi = mid - 1;
            }
            const int bs = (int)bstart[lo];
            const int be = (lo + 1 < nb) ? (int)bstart[lo + 1] : n;
            oa[e] = svals[p] - (float)(bsum[lo] / (double)(be - bs));
        }
        o.x = oa[0]; o.y = oa[1]; o.z = oa[2]; o.w = oa[3];
        *(float4*)(rank_out + t) = o;
    }
}

// ---------------------------------------------------------------------------
extern "C" void kernel_launch(void* const* d_in, const int* in_sizes, int n_in,
                              void* d_out, int out_size, void* d_ws, size_t ws_size,
                              hipStream_t stream) {
    const float* x  = (const float*)d_in[0];
    const float* W1 = (const float*)d_in[1];
    const float* b1 = (const float*)d_in[2];
    const float* W2 = (const float*)d_in[3];
    const float* b2 = (const float*)d_in[4];
    const float* W3 = (const float*)d_in[5];
    const float* b3 = (const float*)d_in[6];
    float* out = (float*)d_out;   // [0,4096): rank, [4096,8192): scores

    const int B = 4096, D_IN = 512, H = 2048;

    char* ws = (char*)d_ws;
    unsigned short* h1  = (unsigned short*)(ws);                    // 16 MB bf16
    unsigned short* xb  = (unsigned short*)(ws + (16u << 20));      //  4 MB bf16
    unsigned short* W1t = (unsigned short*)(ws + (20u << 20));      //  2 MB bf16 [N,K]
    unsigned short* W2t = (unsigned short*)(ws + (22u << 20));      //  8 MB bf16 [N,K]
    float*          sc  = (float*)(ws + (30u << 20));               // 16 KB
    int*            posg= (int*)(ws + (30u << 20) + 16384);         // 16 KB

    // 1) fused prep: convert x, transpose W1/W2, zero sc+posg.
    prep_all<<<2305, 256, 0, stream>>>(x, xb, W1, W1t, W2, W2t, sc, posg);

    // 2) GEMM1: h1 = relu(x @ W1 + b1), bf16. M=4096 N=2048 K=512.
    gemm_bf16_mfma<0><<<dim3(H / 128, B / 256), 512, 0, stream>>>(
        xb, W1t, b1, h1, nullptr, nullptr, B, H, D_IN);
    // 3) GEMM2 fused with layer-3: scores += relu(h1@W2+b2) @ W3.
    gemm_bf16_mfma<1><<<dim3(H / 128, B / 256), 512, 0, stream>>>(
        h1, W2t, b2, nullptr, W3, sc, B, H, H);

    // 4) fused finalize + rank count (256 blocks, keys from sc in-block).
    rank_count<<<dim3(B / 256, B / 256), 256, 0, stream>>>(sc, b3, out + B, posg);
    // 5) PAV + fill.
    pav_fill<<<1, 1024, 0, stream>>>(sc, b3, posg, out);
}

// Round 8
// 139.969 us; speedup vs baseline: 1.4812x; 1.4812x over previous
//
#include <hip/hip_runtime.h>
#include <hip/hip_bf16.h>

typedef float f32x4 __attribute__((ext_vector_type(4)));
typedef __bf16 bf16x8 __attribute__((ext_vector_type(8)));

#define AS3(p) ((__attribute__((address_space(3))) void*)(p))
#define AS1(p) ((const __attribute__((address_space(1))) void*)(p))

__device__ __forceinline__ unsigned short f2bf(float f) {
    unsigned u = __float_as_uint(f);
    return (unsigned short)((u + 0x7fffu + ((u >> 16) & 1u)) >> 16);  // RNE
}

__device__ __forceinline__ unsigned long long sort_key(float v, int idx) {
    unsigned ub = __float_as_uint(v);
    unsigned m  = (ub & 0x80000000u) ? ~ub : (ub | 0x80000000u);  // asc map
    return ((unsigned long long)(~m) << 12) | (unsigned)idx;      // desc, stable
}

// ---------------------------------------------------------------------------
// Fused prep: one dispatch.
//   blocks [0,1024):      x fp32 -> bf16
//   blocks [1024,2304):   W1/W2 transpose+convert (64x64 tiles)
//   block  2304:          zero scores accumulator + posg
// ---------------------------------------------------------------------------
__global__ __launch_bounds__(256) void prep_all(
    const float* __restrict__ x, unsigned short* __restrict__ xb,
    const float* __restrict__ W1, unsigned short* __restrict__ W1t,
    const float* __restrict__ W2, unsigned short* __restrict__ W2t,
    float* __restrict__ sc, int* __restrict__ posg)
{
    __shared__ float tile[64][65];
    const int bx = blockIdx.x;
    const int t = threadIdx.x;

    if (bx < 1024) {                       // convert x
        int i = bx * 2048 + t * 8;
        float4 v0 = *(const float4*)(x + i);
        float4 v1 = *(const float4*)(x + i + 4);
        ushort4 o0 = { f2bf(v0.x), f2bf(v0.y), f2bf(v0.z), f2bf(v0.w) };
        ushort4 o1 = { f2bf(v1.x), f2bf(v1.y), f2bf(v1.z), f2bf(v1.w) };
        *(ushort4*)(xb + i)     = o0;
        *(ushort4*)(xb + i + 4) = o1;
        return;
    }
    if (bx == 2304) {                      // zero sc + posg
        float4 z = {0.f, 0.f, 0.f, 0.f};
        int4 zi = {0, 0, 0, 0};
        #pragma unroll
        for (int i = 0; i < 4; ++i) {
            *(float4*)(sc + t * 16 + i * 4)  = z;
            *(int4*)(posg + t * 16 + i * 4)  = zi;
        }
        return;
    }
    // transpose tiles
    int idx = bx - 1024;
    int ty = idx >> 5;                     // 0..39
    int txi = idx & 31;                    // 0..31
    const float* W; unsigned short* Wt; int K, N, by;
    if (ty < 8) { W = W1; Wt = W1t; K = 512;  N = 2048; by = ty; }
    else        { W = W2; Wt = W2t; K = 2048; N = 2048; by = ty - 8; }

    const int col4 = t & 15;
    const int row  = t >> 4;
    #pragma unroll
    for (int i = 0; i < 4; ++i) {
        int r = row + i * 16;
        float4 v = *(const float4*)(W + (size_t)(by * 64 + r) * N + txi * 64 + col4 * 4);
        tile[r][col4 * 4 + 0] = v.x;
        tile[r][col4 * 4 + 1] = v.y;
        tile[r][col4 * 4 + 2] = v.z;
        tile[r][col4 * 4 + 3] = v.w;
    }
    __syncthreads();
    #pragma unroll
    for (int i = 0; i < 4; ++i) {
        int r = row + i * 16;
        ushort4 o = { f2bf(tile[col4 * 4 + 0][r]), f2bf(tile[col4 * 4 + 1][r]),
                      f2bf(tile[col4 * 4 + 2][r]), f2bf(tile[col4 * 4 + 3][r]) };
        *(ushort4*)(Wt + (size_t)(txi * 64 + r) * K + by * 64 + col4 * 4) = o;
    }
}

// ---------------------------------------------------------------------------
// bf16 MFMA GEMM, 256x128 tile, BK=64, TRIPLE-BUFFERED, prefetch distance 2,
// steady-state s_waitcnt vmcnt(6), ONE raw s_barrier per K-tile placed
// BEFORE the prefetch issue. (R4 schedule — EMPIRICAL OPTIMUM, 140.3 us.
// Falsified alternatives: R5 phase-pinning +3.5, R6 32x32 shape +9.7,
// R7 A-in-registers +67 — all reverted per pre-declared falsifiers.)
// Race analysis: tile t's buffer is overwritten by loads issued at tile t+1
// (for t+3). Every wave's tile-t ds_reads are lgkm-complete before its
// phase-2 MFMAs issue (compiler-inserted waits), hence before it arrives at
// tile t+1's barrier; the overwrite issue is after that barrier. Safe.
// 512 thr = 8 waves (4M x 2N, per-wave 64x64 out), LDS 3x48 KB = 144 KB,
// 1 block/CU (grid 256 = 1/CU exactly). 32 MFMA + 16 ds_read_b128 +
// 6 global_load_lds per tile per thread.
// Swizzle: LDS slot (r,c) holds global chunk c^(r&7), staged via pre-swizzled
// GLOBAL src + linear LDS dest (rule #21); frag reads XOR back -> 2-way bank
// aliasing only (free, m136; conflicts==0 verified R2/R4 PMC). T1 XCD
// swizzle (nwg=256, %8==0, bijective; FETCH -41% verified R2).
// MODE 0: C = relu(A@Bt^T+bias) bf16.  MODE 1: fused layer-3 rank-1 epilogue.
// ---------------------------------------------------------------------------
#define GB_WAITV(n) { asm volatile("s_waitcnt vmcnt(" #n ")" ::: "memory"); \
                      __builtin_amdgcn_sched_barrier(0); }

template <int MODE>
__global__ __launch_bounds__(512, 2) void gemm_bf16_mfma(
    const unsigned short* __restrict__ A, const unsigned short* __restrict__ Bt,
    const float* __restrict__ bias, unsigned short* __restrict__ Cbf,
    const float* __restrict__ w3, float* __restrict__ scores,
    int M, int N, int K)
{
    // 3 buffers; per buffer: A-tile [0, 256*64), B-tile [256*64, 384*64)
    __shared__ __align__(16) unsigned short lds3[3][384 * 64];   // 144 KB
    constexpr int BOFF = 256 * 64;

    const int tid = threadIdx.x;
    const int wave = tid >> 6, lane = tid & 63;

    // T1: XCD-aware block swizzle (bijective: nwg % 8 == 0)
    const unsigned nwg = gridDim.x * gridDim.y;
    const unsigned bid = blockIdx.y * gridDim.x + blockIdx.x;
    const unsigned sbid = (bid & 7u) * (nwg >> 3) + (bid >> 3);
    const int bn = sbid % gridDim.x;
    const int bm = sbid / gridDim.x;

    const int wm = (wave >> 1) * 64;     // 0,64,128,192
    const int wn = (wave & 1) * 64;      // 0,64

    const unsigned short* Ablk = A  + (size_t)(bm * 256) * K;
    const unsigned short* Bblk = Bt + (size_t)(bn * 128) * K;

    const int lc  = lane & 15;
    const int rl4 = lane >> 4;                     // 0..3
    const int srow = lane >> 3;                    // 0..7
    const int sgc  = ((lane & 7) ^ srow) << 3;     // pre-swizzled src chunk (elems)

    f32x4 acc[4][4] = {};
    const int nt = K >> 6;

    unsigned short *Ac = lds3[0], *An = lds3[1], *Asp = lds3[2];

    // stage half 1: A rows [wave*32, +16), B rows [wave*16, +8)
    #define STG_P1(k0, D) {                                                    \
        _Pragma("unroll")                                                      \
        for (int i = 0; i < 2; ++i) {                                          \
            const int ra = wave * 32 + i * 8 + srow;                           \
            __builtin_amdgcn_global_load_lds(                                  \
                AS1(Ablk + (size_t)ra * K + (k0) + sgc),                       \
                AS3((D) + (wave * 32 + i * 8) * 64), 16, 0, 0);                \
        }                                                                      \
        {                                                                      \
            const int rb = wave * 16 + srow;                                   \
            __builtin_amdgcn_global_load_lds(                                  \
                AS1(Bblk + (size_t)rb * K + (k0) + sgc),                       \
                AS3((D) + BOFF + (wave * 16) * 64), 16, 0, 0);                 \
        } }
    // stage half 2: A rows [wave*32+16, +16), B rows [wave*16+8, +8)
    #define STG_P2(k0, D) {                                                    \
        _Pragma("unroll")                                                      \
        for (int i = 2; i < 4; ++i) {                                          \
            const int ra = wave * 32 + i * 8 + srow;                           \
            __builtin_amdgcn_global_load_lds(                                  \
                AS1(Ablk + (size_t)ra * K + (k0) + sgc),                       \
                AS3((D) + (wave * 32 + i * 8) * 64), 16, 0, 0);                \
        }                                                                      \
        {                                                                      \
            const int rb = wave * 16 + 8 + srow;                               \
            __builtin_amdgcn_global_load_lds(                                  \
                AS1(Bblk + (size_t)rb * K + (k0) + sgc),                       \
                AS3((D) + BOFF + (wave * 16 + 8) * 64), 16, 0, 0);             \
        } }

    // prologue: stage tiles 0 and 1 (12 loads outstanding)
    STG_P1(0, Ac);  STG_P2(0, Ac);
    STG_P1(64, An); STG_P2(64, An);

    for (int t = 0; t < nt; ++t) {
        // wait for tile t (oldest 6); keep tile t+1's 6 in flight
        if (t < nt - 1) { GB_WAITV(6); } else { GB_WAITV(0); }
        __builtin_amdgcn_s_barrier();

        const bool pf = (t + 2 < nt);
        const int kpf = (t + 2) << 6;

        // ---- phase 1: issue prefetch half, a-frags + b-half0, 16 MFMA ----
        if (pf) STG_P1(kpf, Asp);
        bf16x8 a[4][2], b[2][2];
        #pragma unroll
        for (int mt = 0; mt < 4; ++mt)
            #pragma unroll
            for (int kk = 0; kk < 2; ++kk)
                a[mt][kk] = *(const bf16x8*)(
                    Ac + (wm + mt * 16 + lc) * 64 + (((kk * 4 + rl4) ^ (lc & 7)) << 3));
        #pragma unroll
        for (int n2 = 0; n2 < 2; ++n2)
            #pragma unroll
            for (int kk = 0; kk < 2; ++kk)
                b[n2][kk] = *(const bf16x8*)(
                    Ac + BOFF + (wn + n2 * 16 + lc) * 64 + (((kk * 4 + rl4) ^ (lc & 7)) << 3));
        __builtin_amdgcn_s_setprio(1);
        #pragma unroll
        for (int mt = 0; mt < 4; ++mt)
            #pragma unroll
            for (int n2 = 0; n2 < 2; ++n2)
                #pragma unroll
                for (int kk = 0; kk < 2; ++kk)
                    acc[mt][n2] = __builtin_amdgcn_mfma_f32_16x16x32_bf16(
                        a[mt][kk], b[n2][kk], acc[mt][n2], 0, 0, 0);
        __builtin_amdgcn_s_setprio(0);

        // ---- phase 2: issue prefetch half, b-half1, 16 MFMA ----
        if (pf) STG_P2(kpf, Asp);
        #pragma unroll
        for (int n2 = 0; n2 < 2; ++n2)
            #pragma unroll
            for (int kk = 0; kk < 2; ++kk)
                b[n2][kk] = *(const bf16x8*)(
                    Ac + BOFF + (wn + 32 + n2 * 16 + lc) * 64 + (((kk * 4 + rl4) ^ (lc & 7)) << 3));
        __builtin_amdgcn_s_setprio(1);
        #pragma unroll
        for (int mt = 0; mt < 4; ++mt)
            #pragma unroll
            for (int n2 = 0; n2 < 2; ++n2)
                #pragma unroll
                for (int kk = 0; kk < 2; ++kk)
                    acc[mt][2 + n2] = __builtin_amdgcn_mfma_f32_16x16x32_bf16(
                        a[mt][kk], b[n2][kk], acc[mt][2 + n2], 0, 0, 0);
        __builtin_amdgcn_s_setprio(0);

        // rotate buffers: consumed -> spare
        unsigned short* tmp = Ac; Ac = An; An = Asp; Asp = tmp;
    }

    #undef STG_P1
    #undef STG_P2

    // Epilogue. C/D frag: col = lane&15, row = (lane>>4)*4 + reg  [m89]
    const int cm0 = bm * 256 + wm;
    const int cn0 = bn * 128 + wn;
    const int lr = (lane >> 4) * 4;

    if (MODE == 0) {
        #pragma unroll
        for (int j = 0; j < 4; ++j) {
            float bv = bias[cn0 + j * 16 + lc];
            #pragma unroll
            for (int mt = 0; mt < 4; ++mt)
                #pragma unroll
                for (int r = 0; r < 4; ++r) {
                    float v = fmaxf(acc[mt][j][r] + bv, 0.0f);
                    size_t idx = (size_t)(cm0 + mt * 16 + lr + r) * N + cn0 + j * 16 + lc;
                    Cbf[idx] = f2bf(v);
                }
        }
    } else {
        float bv[4], w3v[4];
        #pragma unroll
        for (int j = 0; j < 4; ++j) {
            bv[j]  = bias[cn0 + j * 16 + lc];
            w3v[j] = w3[cn0 + j * 16 + lc];
        }
        #pragma unroll
        for (int mt = 0; mt < 4; ++mt)
            #pragma unroll
            for (int r = 0; r < 4; ++r) {
                float p = 0.0f;
                #pragma unroll
                for (int j = 0; j < 4; ++j)
                    p += fmaxf(acc[mt][j][r] + bv[j], 0.0f) * w3v[j];
                p += __shfl_xor(p, 1);
                p += __shfl_xor(p, 2);
                p += __shfl_xor(p, 4);
                p += __shfl_xor(p, 8);
                if (lc == 0)
                    atomicAdd(&scores[cm0 + mt * 16 + lr + r], p);
            }
    }
}

// ---------------------------------------------------------------------------
// Fused finalize + rank count, 2-D tiled (unchanged).
// ---------------------------------------------------------------------------
__global__ __launch_bounds__(256) void rank_count(
    const float* __restrict__ sc, const float* __restrict__ b3,
    float* __restrict__ out_scores, int* __restrict__ posg)
{
    __shared__ unsigned long long kj[256];
    const int t = threadIdx.x;
    const int bi = blockIdx.x, bj = blockIdx.y;
    const int i = bi * 256 + t;
    const float b3v = b3[0];

    {
        int j = bj * 256 + t;
        kj[t] = sort_key(sc[j] + b3v, j);
    }
    float vi = sc[i] + b3v;
    if (bj == 0) out_scores[i] = vi;
    const unsigned long long mykey = sort_key(vi, i);
    __syncthreads();

    int cnt = 0;
    #pragma unroll 32
    for (int j = 0; j < 256; ++j)
        cnt += (kj[j] < mykey) ? 1 : 0;
    atomicAdd(&posg[i], cnt);
}

// ---------------------------------------------------------------------------
// PAV + fill (latency redesign, verified R1: reg-chunk PAV + tree merge).
// ---------------------------------------------------------------------------
__global__ __launch_bounds__(1024) void pav_fill(
    const float* __restrict__ scores, const float* __restrict__ b3,
    const int* __restrict__ posg, float* __restrict__ rank_out)
{
    constexpr int n = 4096;
    __shared__ __align__(16) unsigned char lds[32768 + 16384 + 8192 + 512];
    double* bsum           = (double*)lds;                     // [4096]
    float*  svals          = (float*)(lds + 32768);            // [4096]
    unsigned short* bstart = (unsigned short*)(lds + 49152);   // [4096]
    unsigned short* cnt    = (unsigned short*)(lds + 57344);   // [256]

    const int tid = threadIdx.x;
    const float b3v = b3[0];

    // ---- scatter scores into sorted order (vectorized, 4/thread) ----
    {
        const int t = tid << 2;
        int4 p4 = *(const int4*)(posg + t);
        float4 s4 = *(const float4*)(scores + t);
        svals[p4.x] = s4.x + b3v;
        svals[p4.y] = s4.y + b3v;
        svals[p4.z] = s4.z + b3v;
        svals[p4.w] = s4.w + b3v;
    }
    __syncthreads();

    // ---- Phase A: per-lane PAV on 16-element chunks, 256 lanes ----
    if (tid < 256) {
        const int base = tid << 4;
        float vv[16];
        *(float4*)(vv + 0)  = *(const float4*)(svals + base + 0);
        *(float4*)(vv + 4)  = *(const float4*)(svals + base + 4);
        *(float4*)(vv + 8)  = *(const float4*)(svals + base + 8);
        *(float4*)(vv + 12) = *(const float4*)(svals + base + 12);
        int sp = 0;
        double tsum = 0.0; int tstart = 0;
        #pragma unroll
        for (int s = 0; s < 16; ++s) {
            const int i = base + s;
            double csum = (double)vv[s] - (double)(n - i);
            int cs = i;
            const int ce = i + 1;
            while (sp > 0 &&
                   tsum * (double)(ce - cs) <= csum * (double)(cs - tstart)) {
                csum += tsum; cs = tstart; --sp;
                if (sp > 0) { tsum = bsum[base + sp - 1]; tstart = bstart[base + sp - 1]; }
            }
            bsum[base + sp] = csum;                 // write-through push
            bstart[base + sp] = (unsigned short)cs;
            tsum = csum; tstart = cs; ++sp;
        }
        cnt[tid] = (unsigned short)sp;
    }
    __syncthreads();

    // ---- Phase B: tree merge, 8 rounds ----
    #pragma unroll 1
    for (int r = 0; r < 8; ++r) {
        const int m = 128 >> r;
        if (tid < m) {
            const int W  = 16 << r;
            const int L  = tid * (W << 1);    // left element/slot base
            const int Rb = L + W;             // right base
            int sp = cnt[L >> 4];
            const int cr = cnt[Rb >> 4];
            double tsum = bsum[L + sp - 1];
            int tstart = bstart[L + sp - 1];
            for (int j = 0; j < cr; ++j) {
                double csum = bsum[Rb + j];
                int cs = (int)bstart[Rb + j];
                const int ce = (j + 1 < cr) ? (int)bstart[Rb + j + 1] : (Rb + W);
                while (sp > 0 &&
                       tsum * (double)(ce - cs) <= csum * (double)(cs - tstart)) {
                    csum += tsum; cs = tstart; --sp;
                    if (sp > 0) { tsum = bsum[L + sp - 1]; tstart = bstart[L + sp - 1]; }
                }
                bsum[L + sp] = csum;
                bstart[L + sp] = (unsigned short)cs;
                tsum = csum; tstart = cs; ++sp;
            }
            cnt[L >> 4] = (unsigned short)sp;
        }
        __syncthreads();
    }

    // ---- gather: rank[t] = svals[p] - mean(block(p)), coalesced f4 writes ----
    const int nb = (int)cnt[0];
    {
        const int t = tid << 2;
        int4 p4 = *(const int4*)(posg + t);
        float4 o;
        int pa[4] = { p4.x, p4.y, p4.z, p4.w };
        float oa[4];
        #pragma unroll
        for (int e = 0; e < 4; ++e) {
            const int p = pa[e];
            int lo = 0, hi = nb - 1;
            while (lo < hi) {
                int mid = (lo + hi + 1) >> 1;
                if ((int)bstart[mid] <= p) lo = mid; else hi = mid - 1;
            }
            const int bs = (int)bstart[lo];
            const int be = (lo + 1 < nb) ? (int)bstart[lo + 1] : n;
            oa[e] = svals[p] - (float)(bsum[lo] / (double)(be - bs));
        }
        o.x = oa[0]; o.y = oa[1]; o.z = oa[2]; o.w = oa[3];
        *(float4*)(rank_out + t) = o;
    }
}

// ---------------------------------------------------------------------------
extern "C" void kernel_launch(void* const* d_in, const int* in_sizes, int n_in,
                              void* d_out, int out_size, void* d_ws, size_t ws_size,
                              hipStream_t stream) {
    const float* x  = (const float*)d_in[0];
    const float* W1 = (const float*)d_in[1];
    const float* b1 = (const float*)d_in[2];
    const float* W2 = (const float*)d_in[3];
    const float* b2 = (const float*)d_in[4];
    const float* W3 = (const float*)d_in[5];
    const float* b3 = (const float*)d_in[6];
    float* out = (float*)d_out;   // [0,4096): rank, [4096,8192): scores

    const int B = 4096, D_IN = 512, H = 2048;

    char* ws = (char*)d_ws;
    unsigned short* h1  = (unsigned short*)(ws);                    // 16 MB bf16
    unsigned short* xb  = (unsigned short*)(ws + (16u << 20));      //  4 MB bf16
    unsigned short* W1t = (unsigned short*)(ws + (20u << 20));      //  2 MB bf16 [N,K]
    unsigned short* W2t = (unsigned short*)(ws + (22u << 20));      //  8 MB bf16 [N,K]
    float*          sc  = (float*)(ws + (30u << 20));               // 16 KB
    int*            posg= (int*)(ws + (30u << 20) + 16384);         // 16 KB

    // 1) fused prep: convert x, transpose W1/W2, zero sc+posg.
    prep_all<<<2305, 256, 0, stream>>>(x, xb, W1, W1t, W2, W2t, sc, posg);

    // 2) GEMM1: h1 = relu(x @ W1 + b1), bf16. M=4096 N=2048 K=512.
    gemm_bf16_mfma<0><<<dim3(H / 128, B / 256), 512, 0, stream>>>(
        xb, W1t, b1, h1, nullptr, nullptr, B, H, D_IN);
    // 3) GEMM2 fused with layer-3: scores += relu(h1@W2+b2) @ W3.
    gemm_bf16_mfma<1><<<dim3(H / 128, B / 256), 512, 0, stream>>>(
        h1, W2t, b2, nullptr, W3, sc, B, H, H);

    // 4) fused finalize + rank count (256 blocks, keys from sc in-block).
    rank_count<<<dim3(B / 256, B / 256), 256, 0, stream>>>(sc, b3, out + B, posg);
    // 5) PAV + fill.
    pav_fill<<<1, 1024, 0, stream>>>(sc, b3, posg, out);
}